// Round 2
// baseline (148.388 us; speedup 1.0000x reference)
//
#include <hip/hip_runtime.h>

#define VOCAB 4096
#define QUARTER 1024   // codes scanned per thread (4-way split)

// Empty-asm register barrier: forces the value into a VGPR, preventing
// fma-contraction / reassociation across it. Emits no instruction.
__device__ __forceinline__ float opaque(float x) {
  asm volatile("" : "+v"(x));
  return x;
}

// Prep: pack per-code {e0, e1, e2, ||e||^2_f32} into ws as float4, where
// ||e||^2 is rounded exactly like numpy: ((e0*e0 + e1*e1) + e2*e2), each
// product and sum individually rounded in f32. Also zero the loss slot.
__global__ __launch_bounds__(256) void vq_prep_kernel(
    const float* __restrict__ cb, float4* __restrict__ cw,
    float* __restrict__ loss_slot) {
  int j = blockIdx.x * 256 + threadIdx.x;
  if (j == 0) *loss_slot = 0.0f;
  if (j < VOCAB) {
    float e0 = cb[3 * j + 0];
    float e1 = cb[3 * j + 1];
    float e2 = cb[3 * j + 2];
    float p0 = opaque(e0 * e0);
    float p1 = opaque(e1 * e1);
    float p2 = opaque(e2 * e2);
    float s01 = opaque(p0 + p1);
    float c = opaque(s01 + p2);
    cw[j] = make_float4(e0, e1, e2, c);
  }
}

// Main: block = 256 threads = 64 points x 4 codebook quarters.
__global__ __launch_bounds__(256) void vq_kernel(
    const float* __restrict__ feats, const float4* __restrict__ cw,
    float* __restrict__ out_quant, float* __restrict__ out_idx,
    float* __restrict__ out_loss, int npts) {
  __shared__ float sB[256];
  __shared__ int sI[256];
  __shared__ double sL[64];

  const int tid = threadIdx.x;
  const int lane = tid & 63;
  // quarter id is wave-uniform; force SGPR so code loads become s_load
  const int q = __builtin_amdgcn_readfirstlane(tid >> 6);
  const int p = blockIdx.x * 64 + lane;

  const float x0 = feats[3 * p + 0];
  const float x1 = feats[3 * p + 1];
  const float x2 = feats[3 * p + 2];

  // ||x||^2 exactly as numpy: products rounded, then ((p0+p1)+p2)
  float xp0 = opaque(x0 * x0);
  float xp1 = opaque(x1 * x1);
  float xp2 = opaque(x2 * x2);
  float xs01 = opaque(xp0 + xp1);
  const float a = opaque(xs01 + xp2);

  const float4* cq = cw + q * QUARTER;
  float best = 3.4e38f;
  int bi = 0;
#pragma unroll 4
  for (int j = 0; j < QUARTER; ++j) {
    float4 cd = cq[j];  // wave-uniform address -> s_load_dwordx4
    // BLAS sgemm dot: fma ascending k, fma(x0,e0,0) == single-rounded mul
    float m = fmaf(x2, cd.z, fmaf(x1, cd.y, x0 * cd.x));
    // dist = (a - 2*m) + c, left-to-right f32.
    // (a - 2*m -> fma(-2,m,a) is value-identical: 2*m is exact.)
    float t = a - 2.0f * m;
    float d = t + cd.w;
    if (d < best) { best = d; bi = q * QUARTER + j; }  // strict <: first min
  }
  sB[tid] = best;
  sI[tid] = bi;
  __syncthreads();

  if (tid < 64) {
    // combine quarters in ascending-j order; strict < keeps earliest index
#pragma unroll
    for (int k = 1; k < 4; ++k) {
      float s = sB[tid + 64 * k];
      if (s < best) { best = s; bi = sI[tid + 64 * k]; }
    }
    float4 cd = cw[bi];
    // straight-through: t = q - x (f32), out = x + t (f32), like reference
    float t0 = cd.x - x0, t1 = cd.y - x1, t2 = cd.z - x2;
    out_quant[3 * p + 0] = x0 + t0;
    out_quant[3 * p + 1] = x1 + t1;
    out_quant[3 * p + 2] = x2 + t2;
    out_idx[p] = (float)bi;
    sL[tid] = (double)t0 * t0 + (double)t1 * t1 + (double)t2 * t2;
  }
  __syncthreads();

  if (tid == 0) {
    double s = 0.0;
#pragma unroll 8
    for (int k = 0; k < 64; ++k) s += sL[k];
    // loss = mean((q-x)^2) + 0.25*mean((x-q)^2) = 1.25 * sum / (npts*3)
    atomicAdd(out_loss, (float)(s * (1.25 / ((double)npts * 3.0))));
  }
}

extern "C" void kernel_launch(void* const* d_in, const int* in_sizes, int n_in,
                              void* d_out, int out_size, void* d_ws,
                              size_t ws_size, hipStream_t stream) {
  const float* feats = (const float*)d_in[0];      // (B*L, 3) f32
  const float* cb = (const float*)d_in[1];         // (4096, 3) f32
  const int npts = in_sizes[0] / 3;                // 65536

  float* out = (float*)d_out;
  float* out_quant = out;                          // npts*3 elems
  float* out_idx = out + in_sizes[0];              // npts elems
  float* out_loss = out + in_sizes[0] + npts;      // 1 elem

  float4* cw = (float4*)d_ws;                      // 4096 * 16 B = 64 KB

  vq_prep_kernel<<<VOCAB / 256, 256, 0, stream>>>(cb, cw, out_loss);
  vq_kernel<<<npts / 64, 256, 0, stream>>>(feats, cw, out_quant, out_idx,
                                           out_loss, npts);
}

// Round 3
// 119.664 us; speedup vs baseline: 1.2400x; 1.2400x over previous
//
#include <hip/hip_runtime.h>

#define VOCAB 4096
#define SLICES 8
#define SLICE 512            // codes per slice (8-way split per point)
#define HALF 256             // two contiguous sub-chains per thread for ILP

// Empty-asm register barrier: forces the value into a VGPR, preventing
// fma-contraction / reassociation across it. Emits no instruction.
__device__ __forceinline__ float opaque(float x) {
  asm volatile("" : "+v"(x));
  return x;
}

// Prep: pack per-code {e0, e1, e2, ||e||^2_f32} into ws as float4, where
// ||e||^2 is rounded exactly like numpy: ((e0*e0 + e1*e1) + e2*e2), each
// product and sum individually rounded in f32. Also zero the loss slot.
__global__ __launch_bounds__(256) void vq_prep_kernel(
    const float* __restrict__ cb, float4* __restrict__ cw,
    float* __restrict__ loss_slot) {
  int j = blockIdx.x * 256 + threadIdx.x;
  if (j == 0) *loss_slot = 0.0f;
  if (j < VOCAB) {
    float e0 = cb[3 * j + 0];
    float e1 = cb[3 * j + 1];
    float e2 = cb[3 * j + 2];
    float p0 = opaque(e0 * e0);
    float p1 = opaque(e1 * e1);
    float p2 = opaque(e2 * e2);
    float s01 = opaque(p0 + p1);
    float c = opaque(s01 + p2);
    cw[j] = make_float4(e0, e1, e2, c);
  }
}

// Main: block = 512 threads = 64 points x 8 codebook slices.
// 1024 blocks x 8 waves = 8192 waves = 32 waves/CU (full occupancy).
__global__ __launch_bounds__(512) void vq_kernel(
    const float* __restrict__ feats, const float4* __restrict__ cw,
    float* __restrict__ out_quant, float* __restrict__ out_idx,
    float* __restrict__ out_loss, int npts) {
  __shared__ float sB[512];
  __shared__ int sI[512];
  __shared__ double sL[64];

  const int tid = threadIdx.x;
  const int lane = tid & 63;
  // slice id is wave-uniform; force SGPR so code loads become s_load
  const int s = __builtin_amdgcn_readfirstlane(tid >> 6);
  const int p = blockIdx.x * 64 + lane;

  const float x0 = feats[3 * p + 0];
  const float x1 = feats[3 * p + 1];
  const float x2 = feats[3 * p + 2];

  // ||x||^2 exactly as numpy: products rounded, then ((p0+p1)+p2)
  float xp0 = opaque(x0 * x0);
  float xp1 = opaque(x1 * x1);
  float xp2 = opaque(x2 * x2);
  float xs01 = opaque(xp0 + xp1);
  const float a = opaque(xs01 + xp2);

  const float4* cs = cw + s * SLICE;
  // Two independent argmin chains over contiguous halves [0,256) and
  // [256,512) — breaks the loop-carried cmp->cndmask dependency.
  float bestA = 3.4e38f, bestB = 3.4e38f;
  int biA = 0, biB = 0;
#pragma unroll 4
  for (int j = 0; j < HALF; ++j) {
    float4 cdA = cs[j];         // wave-uniform -> s_load
    float4 cdB = cs[j + HALF];
    // BLAS sgemm dot: fma ascending k; fma(x0,e0,0) == single-rounded mul
    float mA = fmaf(x2, cdA.z, fmaf(x1, cdA.y, x0 * cdA.x));
    float mB = fmaf(x2, cdB.z, fmaf(x1, cdB.y, x0 * cdB.x));
    // dist = (a - 2*m) + c, left-to-right f32 (2*m exact, fma-safe)
    float dA = (a - 2.0f * mA) + cdA.w;
    float dB = (a - 2.0f * mB) + cdB.w;
    if (dA < bestA) { bestA = dA; biA = j; }            // strict <: first min
    if (dB < bestB) { bestB = dB; biB = j + HALF; }
  }
  // combine halves: A has smaller indices, strict < keeps earliest on ties
  float best = bestA;
  int bi = biA;
  if (bestB < best) { best = bestB; bi = biB; }
  bi += s * SLICE;

  sB[tid] = best;
  sI[tid] = bi;
  __syncthreads();

  if (tid < 64) {
    // combine slices in ascending-index order; strict < keeps earliest
#pragma unroll
    for (int k = 1; k < SLICES; ++k) {
      float v = sB[tid + 64 * k];
      if (v < best) { best = v; bi = sI[tid + 64 * k]; }
    }
    float4 cd = cw[bi];
    // straight-through: t = q - x (f32), out = x + t (f32), like reference
    float t0 = cd.x - x0, t1 = cd.y - x1, t2 = cd.z - x2;
    out_quant[3 * p + 0] = x0 + t0;
    out_quant[3 * p + 1] = x1 + t1;
    out_quant[3 * p + 2] = x2 + t2;
    out_idx[p] = (float)bi;
    sL[tid] = (double)t0 * t0 + (double)t1 * t1 + (double)t2 * t2;
  }
  __syncthreads();

  if (tid == 0) {
    double acc = 0.0;
#pragma unroll 8
    for (int k = 0; k < 64; ++k) acc += sL[k];
    // loss = mean((q-x)^2) + 0.25*mean((x-q)^2) = 1.25 * sum / (npts*3)
    atomicAdd(out_loss, (float)(acc * (1.25 / ((double)npts * 3.0))));
  }
}

extern "C" void kernel_launch(void* const* d_in, const int* in_sizes, int n_in,
                              void* d_out, int out_size, void* d_ws,
                              size_t ws_size, hipStream_t stream) {
  const float* feats = (const float*)d_in[0];      // (B*L, 3) f32
  const float* cb = (const float*)d_in[1];         // (4096, 3) f32
  const int npts = in_sizes[0] / 3;                // 65536

  float* out = (float*)d_out;
  float* out_quant = out;                          // npts*3 elems
  float* out_idx = out + in_sizes[0];              // npts elems
  float* out_loss = out + in_sizes[0] + npts;      // 1 elem

  float4* cw = (float4*)d_ws;                      // 4096 * 16 B = 64 KB

  vq_prep_kernel<<<VOCAB / 256, 256, 0, stream>>>(cb, cw, out_loss);
  vq_kernel<<<npts / 64, 512, 0, stream>>>(feats, cw, out_quant, out_idx,
                                           out_loss, npts);
}

// Round 4
// 108.867 us; speedup vs baseline: 1.3630x; 1.0992x over previous
//
#include <hip/hip_runtime.h>

#define VOCAB 4096
#define SLICES 8
#define SLICE 512            // codes per slice (8-way split per point)
#define HALF 256             // pair (j, j+HALF) within a slice -> packed lanes

typedef float v2f __attribute__((ext_vector_type(2)));

// 32-byte pair record: component k of codes (gA, gB) packed as float2.
// Wave-uniform stream -> one s_load_dwordx8 per pair.
struct __align__(32) PkRec {
  v2f c0, c1, c2, cc;
};

// Empty-asm register barrier: forces the value into a VGPR, preventing
// fma-contraction / reassociation across it. Emits no instruction.
__device__ __forceinline__ float opaque(float x) {
  asm volatile("" : "+v"(x));
  return x;
}

// Prep: one thread per pair record r in [0, 2048).
// Slice s = r>>8, j = r&255; codes gA = s*512 + j, gB = gA + 256.
// cc = ((e0*e0 + e1*e1) + e2*e2) rounded exactly like numpy (each product
// and sum individually rounded f32). Also zero the loss slot.
__global__ __launch_bounds__(256) void vq_prep_kernel(
    const float* __restrict__ cb, PkRec* __restrict__ cw,
    float* __restrict__ loss_slot) {
  int r = blockIdx.x * 256 + threadIdx.x;
  if (r == 0) *loss_slot = 0.0f;
  if (r >= (VOCAB / 2)) return;
  int s = r >> 8;
  int j = r & (HALF - 1);
  int gA = s * SLICE + j;
  int gB = gA + HALF;

  float a0 = cb[3 * gA + 0], a1 = cb[3 * gA + 1], a2 = cb[3 * gA + 2];
  float b0 = cb[3 * gB + 0], b1 = cb[3 * gB + 1], b2 = cb[3 * gB + 2];

  float pa0 = opaque(a0 * a0), pa1 = opaque(a1 * a1), pa2 = opaque(a2 * a2);
  float ccA = opaque(opaque(pa0 + pa1) + pa2);
  float pb0 = opaque(b0 * b0), pb1 = opaque(b1 * b1), pb2 = opaque(b2 * b2);
  float ccB = opaque(opaque(pb0 + pb1) + pb2);

  PkRec rec;
  rec.c0 = (v2f){a0, b0};
  rec.c1 = (v2f){a1, b1};
  rec.c2 = (v2f){a2, b2};
  rec.cc = (v2f){ccA, ccB};
  cw[r] = rec;
}

// Main: block = 512 threads = 64 points x 8 codebook slices.
// 1024 blocks x 8 waves = 8192 waves -> 32 waves/CU.
__global__ __launch_bounds__(512) void vq_kernel(
    const float* __restrict__ feats, const PkRec* __restrict__ cw,
    const float* __restrict__ cb, float* __restrict__ out_quant,
    float* __restrict__ out_idx, float* __restrict__ out_loss, int npts) {
  __shared__ float sB[512];
  __shared__ int sI[512];
  __shared__ double sL[64];

  const int tid = threadIdx.x;
  const int lane = tid & 63;
  // slice id is wave-uniform; force SGPR so pair records stream via s_load
  const int s = __builtin_amdgcn_readfirstlane(tid >> 6);
  const int p = blockIdx.x * 64 + lane;

  const float x0 = feats[3 * p + 0];
  const float x1 = feats[3 * p + 1];
  const float x2 = feats[3 * p + 2];

  // ||x||^2 exactly as numpy: products rounded, then ((p0+p1)+p2)
  float xp0 = opaque(x0 * x0);
  float xp1 = opaque(x1 * x1);
  float xp2 = opaque(x2 * x2);
  const float a = opaque(opaque(xp0 + xp1) + xp2);

  const v2f xx0 = (v2f){x0, x0};
  const v2f xx1 = (v2f){x1, x1};
  const v2f xx2 = (v2f){x2, x2};
  const v2f aa = (v2f){a, a};
  const v2f n2 = (v2f){-2.0f, -2.0f};

  const PkRec* recs = cw + s * HALF;
  // Two argmin chains (codes j and j+256 of this slice) ride the two packed
  // lanes; both cndmasks share the same relative-j value.
  float bestA = 3.4e38f, bestB = 3.4e38f;
  int jA = 0, jB = 0;
#pragma unroll 8
  for (int j = 0; j < HALF; ++j) {
    PkRec r = recs[j];                 // s_load_dwordx8 (wave-uniform)
    // packed dot, fma ascending k: per-half rounding == scalar fmaf chain
    v2f m = r.c0 * xx0;                // v_pk_mul_f32
    m = r.c1 * xx1 + m;                // v_pk_fma_f32 (contract)
    m = r.c2 * xx2 + m;                // v_pk_fma_f32
    v2f t = m * n2 + aa;               // v_pk_fma_f32: a - 2m (2m exact)
    v2f d = t + r.cc;                  // v_pk_add_f32: (a-2m) + c
    if (d.x < bestA) { bestA = d.x; jA = j; }   // strict <: first min
    if (d.y < bestB) { bestB = d.y; jB = j; }
  }
  // combine halves: A spans lower indices; strict < keeps earliest on ties
  float best = bestA;
  int bi = s * SLICE + jA;
  if (bestB < best) { best = bestB; bi = s * SLICE + HALF + jB; }

  sB[tid] = best;
  sI[tid] = bi;
  __syncthreads();

  if (tid < 64) {
    // combine slices in ascending-index order; strict < keeps earliest
#pragma unroll
    for (int k = 1; k < SLICES; ++k) {
      float v = sB[tid + 64 * k];
      if (v < best) { best = v; bi = sI[tid + 64 * k]; }
    }
    float q0 = cb[3 * bi + 0];
    float q1 = cb[3 * bi + 1];
    float q2 = cb[3 * bi + 2];
    // straight-through: t = q - x (f32), out = x + t (f32), like reference
    float t0 = q0 - x0, t1 = q1 - x1, t2 = q2 - x2;
    out_quant[3 * p + 0] = x0 + t0;
    out_quant[3 * p + 1] = x1 + t1;
    out_quant[3 * p + 2] = x2 + t2;
    out_idx[p] = (float)bi;
    sL[tid] = (double)t0 * t0 + (double)t1 * t1 + (double)t2 * t2;
  }
  __syncthreads();

  if (tid == 0) {
    double acc = 0.0;
#pragma unroll 8
    for (int k = 0; k < 64; ++k) acc += sL[k];
    // loss = mean((q-x)^2) + 0.25*mean((x-q)^2) = 1.25 * sum / (npts*3)
    atomicAdd(out_loss, (float)(acc * (1.25 / ((double)npts * 3.0))));
  }
}

extern "C" void kernel_launch(void* const* d_in, const int* in_sizes, int n_in,
                              void* d_out, int out_size, void* d_ws,
                              size_t ws_size, hipStream_t stream) {
  const float* feats = (const float*)d_in[0];      // (B*L, 3) f32
  const float* cb = (const float*)d_in[1];         // (4096, 3) f32
  const int npts = in_sizes[0] / 3;                // 65536

  float* out = (float*)d_out;
  float* out_quant = out;                          // npts*3 elems
  float* out_idx = out + in_sizes[0];              // npts elems
  float* out_loss = out + in_sizes[0] + npts;      // 1 elem

  PkRec* cw = (PkRec*)d_ws;                        // 2048 * 32 B = 64 KB

  vq_prep_kernel<<<(VOCAB / 2) / 256, 256, 0, stream>>>(cb, cw, out_loss);
  vq_kernel<<<npts / 64, 512, 0, stream>>>(feats, cw, cb, out_quant, out_idx,
                                           out_loss, npts);
}